// Round 4
// baseline (27.096 us; speedup 1.0000x reference)
//
#include <hip/hip_runtime.h>
#include <hip/hip_fp16.h>

#define NB     8
#define NDEP   64
#define KK     512
#define NP     12
#define NT     550
#define KSPLIT 2
#define KCH    (KK / KSPLIT)   // 256 k's per block == blockDim
#define WIN    32              // tick window per n, centered on floor(z)

static __device__ inline unsigned packh2(float a, float b) {
    __half2 h = __floats2half2_rn(a, b);
    return __builtin_bit_cast(unsigned, h);
}
static __device__ inline float2 unpackh2(unsigned u) {
    return __half22float2(__builtin_bit_cast(__half2, u));
}

__global__ __launch_bounds__(256) void next_sim_kernel(
    const float* __restrict__ ed,      // (8,64,4) x,y,z,E
    const float* __restrict__ edraw,   // (8,64)
    const float* __restrict__ ddraw,   // (8,64,512,3)
    const float* __restrict__ udraw,   // (8,64,512)
    const float* __restrict__ W1,      // (2,28)
    const float* __restrict__ b1,      // (28)
    const float* __restrict__ W2,      // (28,12)
    const float* __restrict__ b2,      // (12)
    const float* __restrict__ dscale,  // (3)
    const float* __restrict__ pscale,  // (12)
    const float* __restrict__ life,    // (1)
    float* __restrict__ out)           // (8,12,550)
{
    // 16 KB dual-purpose buffer:
    //   phase 1/2: rows[k] = 2x uint4 {pm[0..7] fp16, pm[8..11] fp16, ez f32, pad}
    //   phase 2/3: partials[tid][16] f32 (12 used)
    __shared__ __align__(16) float smem[4096];
    uint4* rows = reinterpret_cast<uint4*>(smem);
    __shared__ float sW1[56], sb1[28], sW2[336], sb2[12], sS2[12], sD2[3];
    __shared__ int   wcnt[4];

    const int tid = threadIdx.x;
    const int bid = blockIdx.x;
    const int b   = bid / (NDEP * KSPLIT);
    const int rem = bid % (NDEP * KSPLIT);
    const int n   = rem / KSPLIT;
    const int ks  = rem % KSPLIT;
    const int bn  = b * NDEP + n;

    for (int i = tid; i < 336; i += 256) sW2[i] = W2[i];
    if (tid < 56) sW1[tid] = W1[tid];
    if (tid < 28) sb1[tid] = b1[tid];
    if (tid < 12) sb2[tid] = b2[tid];
    if (tid < 12) { float s = pscale[tid]; sS2[tid] = s * s; }
    if (tid < 3)  { float s = dscale[tid]; sD2[tid] = s * s; }
    __syncthreads();

    const float4 dep  = ((const float4*)ed)[bn];   // x,y,z,E
    const float nval  = dep.w * (1000000.0f / 22.4f);
    const float sigma = sqrtf(0.15f * nval);
    int ne = (int)(sigma * edraw[bn] + nval);      // trunc toward 0 == astype(int32)
    ne = min(max(ne, 0), KK);
    const float sqz     = sqrtf(dep.z);
    const float invLife = 1.0f / life[0];
    const int   t_base  = (int)floorf(dep.z) - WIN / 2;   // in [34,484]: window always in-bounds

    // ---- phase 1a: survival test + block-level compaction offsets
    const int kk = ks * KCH + tid;
    const float* dd = ddraw + ((size_t)bn * KK + kk) * 3;
    const float d0 = dd[0], d1 = dd[1], d2 = dd[2];
    const float ez = fmaf(sD2[2] * d2, sqz, dep.z);
    const float prob = 1.0f - __expf(-ez * invLife);
    const bool live = (kk < ne) && (prob > udraw[(size_t)bn * KK + kk]);

    const unsigned long long bal = __ballot(live);
    const int lane = tid & 63;
    const int wv   = tid >> 6;
    if (lane == 0) wcnt[wv] = __popcll(bal);
    __syncthreads();

    const int c0 = wcnt[0], c1 = wcnt[1], c2 = wcnt[2], c3 = wcnt[3];
    const int live_total = c0 + c1 + c2 + c3;
    if (live_total == 0) return;                  // uniform: whole block dead (common for ks=1)
    int base = 0;
    if (wv > 0) base += c0;
    if (wv > 1) base += c1;
    if (wv > 2) base += c2;

    // ---- phase 1b: MLP only for survivors; write compacted fp16 row
    if (live) {
        const int slot = base + __popcll(bal & ((1ull << lane) - 1ull));
        const float ex = fmaf(sD2[0] * d0, sqz, dep.x);
        const float ey = fmaf(sD2[1] * d1, sqz, dep.y);

        float pm[NP];
        #pragma unroll
        for (int p = 0; p < NP; ++p) pm[p] = sb2[p];
        #pragma unroll 4
        for (int j = 0; j < 28; ++j) {
            float hj = fmaf(sW1[j], ex, fmaf(sW1[28 + j], ey, sb1[j]));
            hj = 1.0f / (1.0f + __expf(-hj));
            #pragma unroll
            for (int p = 0; p < NP; ++p) pm[p] = fmaf(hj, sW2[j * NP + p], pm[p]);
        }
        #pragma unroll
        for (int p = 0; p < NP; ++p) pm[p] = sS2[p] / (1.0f + __expf(-pm[p]));

        uint4 r0, r1;
        r0.x = packh2(pm[0], pm[1]);  r0.y = packh2(pm[2],  pm[3]);
        r0.z = packh2(pm[4], pm[5]);  r0.w = packh2(pm[6],  pm[7]);
        r1.x = packh2(pm[8], pm[9]);  r1.y = packh2(pm[10], pm[11]);
        r1.z = __builtin_bit_cast(unsigned, ez);  r1.w = 0u;
        rows[2 * slot]     = r0;
        rows[2 * slot + 1] = r1;
    }
    __syncthreads();

    // ---- phase 2: dense gather over compacted rows. thread = (t_rel, k-chunk)
    const int   tw    = tid & (WIN - 1);
    const int   chunk = tid >> 5;                 // 0..7
    const int   L     = (live_total + 7) >> 3;    // k's per chunk (uniform)
    const float tc    = (float)(t_base + tw) + 0.5f;
    float4 a0 = {0,0,0,0}, a1 = {0,0,0,0}, a2 = {0,0,0,0};
    #pragma unroll 2
    for (int i = 0; i < L; ++i) {
        const int  k     = chunk * L + i;
        const bool vld   = (k < live_total);
        const int  kc    = vld ? k : 0;
        const uint4 r0 = rows[2 * kc];
        const uint4 r1 = rows[2 * kc + 1];
        const float d  = tc - __builtin_bit_cast(float, r1.z);
        float g = 3.9894228040143274f * __expf(-10.0f * d * d);  // exact 0 outside window
        g = vld ? g : 0.0f;
        const float2 q0 = unpackh2(r0.x), q1 = unpackh2(r0.y);
        const float2 q2 = unpackh2(r0.z), q3 = unpackh2(r0.w);
        const float2 q4 = unpackh2(r1.x), q5 = unpackh2(r1.y);
        a0.x = fmaf(q0.x, g, a0.x); a0.y = fmaf(q0.y, g, a0.y);
        a0.z = fmaf(q1.x, g, a0.z); a0.w = fmaf(q1.y, g, a0.w);
        a1.x = fmaf(q2.x, g, a1.x); a1.y = fmaf(q2.y, g, a1.y);
        a1.z = fmaf(q3.x, g, a1.z); a1.w = fmaf(q3.y, g, a1.w);
        a2.x = fmaf(q4.x, g, a2.x); a2.y = fmaf(q4.y, g, a2.y);
        a2.z = fmaf(q5.x, g, a2.z); a2.w = fmaf(q5.y, g, a2.w);
    }
    __syncthreads();   // all reads of rows[] done before overwriting with partials

    {   // park partials at stride 16 floats (64 B)
        float4* prow = reinterpret_cast<float4*>(&smem[tid * 16]);
        prow[0] = a0; prow[1] = a1; prow[2] = a2;
    }
    __syncthreads();

    // ---- phase 3: reduce 8 chunk-partials, windowed global writeback
    float* outB = out + (size_t)b * NP * NT;
    for (int idx = tid; idx < WIN * NP; idx += 256) {
        const int t_rel = idx / NP;
        const int p     = idx - t_rel * NP;
        float s = 0.0f;
        #pragma unroll
        for (int c = 0; c < 8; ++c) s += smem[(c * WIN + t_rel) * 16 + p];
        if (s != 0.0f) atomicAdd(&outB[p * NT + (t_base + t_rel)], s);
    }
}

extern "C" void kernel_launch(void* const* d_in, const int* in_sizes, int n_in,
                              void* d_out, int out_size, void* d_ws, size_t ws_size,
                              hipStream_t stream) {
    const float* ed     = (const float*)d_in[0];
    const float* edraw  = (const float*)d_in[1];
    const float* ddraw  = (const float*)d_in[2];
    const float* udraw  = (const float*)d_in[3];
    const float* W1     = (const float*)d_in[4];
    const float* b1     = (const float*)d_in[5];
    const float* W2     = (const float*)d_in[6];
    const float* b2     = (const float*)d_in[7];
    const float* dscale = (const float*)d_in[8];
    const float* pscale = (const float*)d_in[9];
    const float* life   = (const float*)d_in[10];
    float* out = (float*)d_out;

    hipMemsetAsync(d_out, 0, (size_t)out_size * sizeof(float), stream);
    next_sim_kernel<<<NB * NDEP * KSPLIT, 256, 0, stream>>>(
        ed, edraw, ddraw, udraw, W1, b1, W2, b2, dscale, pscale, life, out);
}